// Round 4
// baseline (7500.330 us; speedup 1.0000x reference)
//
#include <hip/hip_runtime.h>
#include <stdint.h>

namespace {

constexpr int H = 512;
constexpr int V = 64;     // vocab incl. think-end
constexpr int B = 8;
constexpr int T = 48;
constexpr int D1 = 49;    // delay slots
constexpr int P = 4;      // i-partitions (deterministic split reduction)
constexpr int CH = H / P; // 128
constexpr int NDEC = 45;  // N = T-3
constexpr int NIT = 9 + NDEC; // think iters + decode iters = 54
constexpr int NSTEP = T + NIT; // 102

constexpr int NBLK = 128;     // persistent blocks (<=256 CUs, co-resident)
constexpr int TPB  = 1024;    // 16 waves
constexpr int GSZ  = NBLK * TPB;

// ws layout (in floats)
constexpr size_t SZ_BUF   = (size_t)P * D1 * B * H;          // 802816
constexpr size_t OFF_BUF  = 0;
constexpr size_t OFF_HACT = OFF_BUF + SZ_BUF;                // B*H
constexpr size_t OFF_CUR  = OFF_HACT + (size_t)B * H;        // B*V
constexpr size_t OFF_NOISE= OFF_CUR + (size_t)B * V;         // B*NIT*V
constexpr size_t OFF_INT  = OFF_NOISE + (size_t)B * NIT * V; // 32 ints
// ints: [0..7]=ptr  [8..15]=done  [16..23]=sc_active  [24..31]=sc_base
constexpr size_t OFF_BAR  = OFF_INT + 64;                    // barrier (2 ints)

__device__ __forceinline__ void tf2x32(uint32_t k0, uint32_t k1,
                                       uint32_t& x0, uint32_t& x1) {
  const uint32_t ks2 = k0 ^ k1 ^ 0x1BD11BDAu;
  x0 += k0; x1 += k1;
#define RR(r) { x0 += x1; x1 = (x1 << (r)) | (x1 >> (32-(r))); x1 ^= x0; }
  RR(13) RR(15) RR(26) RR(6)  x0 += k1;  x1 += ks2 + 1u;
  RR(17) RR(29) RR(16) RR(24) x0 += ks2; x1 += k0 + 2u;
  RR(13) RR(15) RR(26) RR(6)  x0 += k0;  x1 += k1 + 3u;
  RR(17) RR(29) RR(16) RR(24) x0 += k1;  x1 += ks2 + 4u;
  RR(13) RR(15) RR(26) RR(6)  x0 += ks2; x1 += k0 + 5u;
#undef RR
}

__device__ __forceinline__ float gumbel_from_bits(uint32_t bits) {
  float u = __uint_as_float((bits >> 9) | 0x3F800000u) - 1.0f;
  u = u + 1e-9f;
  return -logf(-logf(u));
}

// device-scope sense(counter)-style grid barrier; bar[0]=arrive cnt, bar[1]=epoch
__device__ __forceinline__ void gsync(int* bar, int iter) {
  __syncthreads();
  if (threadIdx.x == 0) {
    __threadfence();
    int old = __hip_atomic_fetch_add(&bar[0], 1, __ATOMIC_ACQ_REL,
                                     __HIP_MEMORY_SCOPE_AGENT);
    if (old == NBLK - 1) {
      __hip_atomic_store(&bar[0], 0, __ATOMIC_RELAXED, __HIP_MEMORY_SCOPE_AGENT);
      __hip_atomic_store(&bar[1], iter, __ATOMIC_RELEASE, __HIP_MEMORY_SCOPE_AGENT);
    } else {
      int guard = 0;
      while (__hip_atomic_load(&bar[1], __ATOMIC_ACQUIRE,
                               __HIP_MEMORY_SCOPE_AGENT) < iter) {
        __builtin_amdgcn_s_sleep(4);
        if (++guard > (1 << 22)) break;   // fail-visible, never hangs
      }
    }
    __threadfence();
  }
  __syncthreads();
}

__global__ __launch_bounds__(64) void k_zero(float* __restrict__ ws) {
  int* bar = (int*)(ws + OFF_BAR);
  if (threadIdx.x < 2) bar[threadIdx.x] = 0;
}

__global__ __launch_bounds__(TPB, 4) void k_main(
    const float* __restrict__ x,  const float* __restrict__ wa,
    const float* __restrict__ ba, const float* __restrict__ lat,
    const float* __restrict__ tau,const float* __restrict__ we,
    const float* __restrict__ be, float* __restrict__ ws,
    float* __restrict__ out) {
  float* bufP  = ws + OFF_BUF;
  float* hact  = ws + OFF_HACT;
  float* cur   = ws + OFF_CUR;
  float* noise = ws + OFF_NOISE;
  int*   ib    = (int*)(ws + OFF_INT);
  int*   bar   = (int*)(ws + OFF_BAR);

  const int blk  = blockIdx.x;
  const int tid  = threadIdx.x;
  const int wave = tid >> 6;
  const int lane = tid & 63;
  const int p      = blk >> 5;          // 0..3 (i-partition)
  const int hoBase = (blk & 31) << 4;   // 16 consecutive ho per block
  const int ho     = hoBase + wave;     // this wave's output row

  __shared__ float s_hact[B * CH];   // 4 KB: h slice for scat
  __shared__ float s_hdel[H];        // control: delayed state
  __shared__ float s_cur[V];
  __shared__ float s_red[256];
  __shared__ int   s_act[B], s_base[B];

  int bc = 0;  // barrier epoch

  // ---------------- init (every call: ws is not re-poisoned) ----------------
  {
    int gtid = blk * TPB + tid;
    for (size_t i = (size_t)gtid; i < SZ_BUF; i += GSZ) bufP[i] = 0.0f;
    if (gtid < B * NIT * V) {   // partitionable threefry noise table
      int j = gtid & 63; int rest = gtid >> 6;
      int it = rest % NIT; int s = rest / NIT;
      uint32_t ka = 0u, kb = (uint32_t)s;
      tf2x32(0u, 42u, ka, kb);                 // split -> key_s
      uint32_t data = (it < 9) ? (uint32_t)it : (uint32_t)(10000 + (it - 9));
      uint32_t e = 0u, f = data;
      tf2x32(ka, kb, e, f);                    // fold_in -> iter key
      uint32_t x0 = 0u, x1 = (uint32_t)j;
      tf2x32(e, f, x0, x1);                    // counter-mode block
      noise[((size_t)s * NIT + it) * V + j] = gumbel_from_bits(x0 ^ x1);
    }
    if (gtid >= 32768 && gtid < 32768 + B * V) {
      int v2 = gtid - 32768; int b = v2 >> 6; int o = v2 & 63;
      cur[v2] = x[((size_t)b * T + (T - 1)) * V + o];
    }
    if (gtid >= 33792 && gtid < 33824) ib[gtid - 33792] = 0;
  }
  gsync(bar, ++bc);

  // ---------------- 102 sequential steps ----------------
  for (int t = 0; t < NSTEP; ++t) {
    const int mode = (t < T) ? 0 : ((t < T + 9) ? 1 : 2); // enc/think/dec

    // ===== phase A: control (blocks 0..7, one per sample) =====
    if (blk < B) {
      const int b = blk;
      const int ptr = ib[b];
      const int dn  = ib[8 + b];
      const int active = (mode == 1) ? (dn ? 0 : 1) : 1;

      if (tid < H) {   // h_del = sum of P partials (fixed order)
        float hd = 0.0f;
        #pragma unroll
        for (int p2 = 0; p2 < P; ++p2)
          hd += bufP[(((size_t)p2 * D1 + ptr) * B + b) * H + tid];
        s_hdel[tid] = hd;
      }
      if (tid >= H && tid < H + V) {
        int o = tid - H;
        s_cur[o] = (mode == 0) ? x[((size_t)b * T + t) * V + o] : cur[b * V + o];
      }
      __syncthreads();

      if (tid < H) {   // h = tanh(W_a @ in + ba + h_del)
        float acc = ba[tid] + s_hdel[tid];
        const float* war = wa + (size_t)tid * V;
        #pragma unroll
        for (int v = 0; v < V; v += 4) {
          float4 w4 = *(const float4*)(war + v);
          acc = fmaf(w4.x, s_cur[v],     acc);
          acc = fmaf(w4.y, s_cur[v + 1], acc);
          acc = fmaf(w4.z, s_cur[v + 2], acc);
          acc = fmaf(w4.w, s_cur[v + 3], acc);
        }
        hact[(size_t)b * H + tid] = tanhf(acc);
      } else if (mode > 0 && tid >= 512 && tid < 768) {
        // y partials: identical arithmetic to the passing round-3 kernel
        int r = tid - 512, o = r >> 2, q = r & 3;
        const float* wer = we + (size_t)o * H + q * CH;
        const float* hp  = s_hdel + q * CH;
        float acc = 0.0f;
        for (int i2 = 0; i2 < CH; i2 += 4) {
          float4 w4 = *(const float4*)(wer + i2);
          acc = fmaf(w4.x, hp[i2],     acc);
          acc = fmaf(w4.y, hp[i2 + 1], acc);
          acc = fmaf(w4.z, hp[i2 + 2], acc);
          acc = fmaf(w4.w, hp[i2 + 3], acc);
        }
        s_red[r] = acc;
      }
      __syncthreads();

      if (mode > 0 && tid < V) {
        const int o = tid;
        const int it = t - T;
        float y = ((s_red[o*4] + s_red[o*4+1]) + (s_red[o*4+2] + s_red[o*4+3]))
                  + be[o];
        if (mode == 2 && o < V - 1)
          out[((size_t)b * NDEC + (t - T - 9)) * (V - 1) + o] = y;
        // gumbel-hard argmax (butterfly; all lanes end with winner)
        float bv = y + noise[((size_t)b * NIT + it) * V + o];
        int bi = o;
        #pragma unroll
        for (int m = 32; m >= 1; m >>= 1) {
          float ov = __shfl_xor(bv, m, 64);
          int   oi = __shfl_xor(bi, m, 64);
          if (ov > bv || (ov == bv && oi < bi)) { bv = ov; bi = oi; }
        }
        const int idx = bi;
        if (active) cur[b * V + o] = (o == idx) ? 1.0f : 0.0f;
        if (o == 0) {
          ib[16 + b] = active;
          ib[24 + b] = ptr;
          if (active) ib[b] = (ptr + 1 == D1) ? 0 : ptr + 1;
          if (mode == 1)
            ib[8 + b] = dn | ((idx == 63) ? 1 : 0) | ((it == 8) ? 1 : 0);
        }
      } else if (mode == 0 && tid == 0) {
        ib[16 + b] = 1;
        ib[24 + b] = ptr;
        ib[b] = (ptr + 1 == D1) ? 0 : ptr + 1;
      }
    }
    gsync(bar, ++bc);

    // ===== phase B: scatter (all blocks; block-owned buf regions) =====
    {
      // stage h slice + control ints into LDS
      {
        int b2 = tid >> 7, k2 = tid & 127;
        s_hact[tid] = hact[((size_t)b2 << 9) + p * CH + k2];
        if (tid < B)      s_act[tid]  = ib[16 + tid];
        else if (tid < 2*B) s_base[tid - B] = ib[24 + (tid - B)];
      }
      __syncthreads();

      const float dd  = (float)lane;
      const float inv = 1.0f / 24.0f;
      const float inv2 = inv * inv;
      float acc[B];
      #pragma unroll
      for (int b = 0; b < B; ++b) acc[b] = 0.0f;
      const float* taur = tau + (size_t)ho * H + p * CH;
      const float* latr = lat + (size_t)ho * H + p * CH;
      for (int ii = 0; ii < CH; ii += 4) {
        float4 t4 = *(const float4*)(taur + ii);
        float4 l4 = *(const float4*)(latr + ii);
        float4 h4[B];
        #pragma unroll
        for (int b = 0; b < B; ++b)
          h4[b] = *(const float4*)(&s_hact[b * CH + ii]);
        const float* tp = (const float*)&t4;
        const float* lp = (const float*)&l4;
        #pragma unroll
        for (int k = 0; k < 4; ++k) {
          float tc = fminf(fmaxf(tp[k], 1.0f), 48.0f);
          float cr = fmaxf(0.0f, inv - fabsf((dd - tc) * inv2));
          float q  = cr * lp[k];
          #pragma unroll
          for (int b = 0; b < B; ++b)
            acc[b] = fmaf(q, ((const float*)&h4[b])[k], acc[b]);
        }
      }
      if (lane >= 1 && lane <= 48) {
        #pragma unroll
        for (int b = 0; b < B; ++b) {
          if (s_act[b]) {
            int slot = s_base[b] + lane; if (slot >= D1) slot -= D1;
            bufP[(((size_t)p * D1 + slot) * B + b) * H + ho] += acc[b];
          }
        }
      } else if (lane == 49) {
        // clear the slot that phase A just consumed (owner-local, race-free)
        #pragma unroll
        for (int b = 0; b < B; ++b)
          if (s_act[b])
            bufP[(((size_t)p * D1 + s_base[b]) * B + b) * H + ho] = 0.0f;
      }
    }
    gsync(bar, ++bc);
  }
}

} // anonymous namespace

extern "C" void kernel_launch(void* const* d_in, const int* in_sizes, int n_in,
                              void* d_out, int out_size, void* d_ws, size_t ws_size,
                              hipStream_t stream) {
  (void)in_sizes; (void)n_in; (void)out_size; (void)ws_size;
  const float* x   = (const float*)d_in[0];
  const float* wa  = (const float*)d_in[1];
  const float* ba  = (const float*)d_in[2];
  const float* lat = (const float*)d_in[3];
  const float* tau = (const float*)d_in[4];
  const float* we  = (const float*)d_in[5];
  const float* be  = (const float*)d_in[6];
  float* out = (float*)d_out;
  float* ws  = (float*)d_ws;

  k_zero<<<dim3(1), dim3(64), 0, stream>>>(ws);
  k_main<<<dim3(NBLK), dim3(TPB), 0, stream>>>(x, wa, ba, lat, tau, we, be, ws, out);
}

// Round 5
// 3104.237 us; speedup vs baseline: 2.4162x; 2.4162x over previous
//
#include <hip/hip_runtime.h>
#include <stdint.h>

namespace {

constexpr int H = 512, V = 64, B = 8, T = 48, D1 = 49, NDEC = 45, NSTEP = 102;
constexpr int NBLK = 256, TPB = 512;
constexpr int NG = 8, GMEM = NBLK / NG;

// buf layout: [p2][g][slot][b][hl] ; p2<4 (input chunk), g<64, slot<49, b<8, hl<8
// flat = (p2*64+g)*3136 + slot*64 + b*8 + hl   (3136 = 49*64)
constexpr size_t SZ_BUF  = (size_t)4 * 64 * D1 * B * 8;   // 802816 floats
constexpr size_t OFF_IDX = SZ_BUF;                        // NSTEP*8 ints
constexpr size_t OFF_BAR = OFF_IDX + (size_t)NSTEP * B;   // 512 ints
constexpr size_t P2STRIDE = (size_t)64 * 3136;            // 200704

__device__ __forceinline__ void tf2x32(uint32_t k0, uint32_t k1,
                                       uint32_t& x0, uint32_t& x1) {
  const uint32_t ks2 = k0 ^ k1 ^ 0x1BD11BDAu;
  x0 += k0; x1 += k1;
#define RR(r) { x0 += x1; x1 = (x1 << (r)) | (x1 >> (32-(r))); x1 ^= x0; }
  RR(13) RR(15) RR(26) RR(6)  x0 += k1;  x1 += ks2 + 1u;
  RR(17) RR(29) RR(16) RR(24) x0 += ks2; x1 += k0 + 2u;
  RR(13) RR(15) RR(26) RR(6)  x0 += k0;  x1 += k1 + 3u;
  RR(17) RR(29) RR(16) RR(24) x0 += k1;  x1 += ks2 + 4u;
  RR(13) RR(15) RR(26) RR(6)  x0 += ks2; x1 += k0 + 5u;
#undef RR
}

__device__ __forceinline__ float gumbel_from_bits(uint32_t bits) {
  float u = __uint_as_float((bits >> 9) | 0x3F800000u) - 1.0f;
  u = u + 1e-9f;
  return -logf(-logf(u));
}

__global__ __launch_bounds__(512) void k_zero(float* __restrict__ ws) {
  int* bar = (int*)ws + OFF_BAR;
  bar[threadIdx.x] = 0;
}

// two-level grid barrier: relaxed monotone counters, ONE release/acquire fence
// pair per block per step. bar[0]=global cnt; bar[16+16g]=group cnt;
// bar[160+16g]=group release epoch.
__device__ __forceinline__ void gbar(int* bar, int grp, int ep) {
  __syncthreads();   // drains each thread's vmcnt -> stores are at L2
  if (threadIdx.x == 0) {
    __builtin_amdgcn_fence(__ATOMIC_RELEASE, "agent");   // wbl2 once
    int old = __hip_atomic_fetch_add(&bar[16 + 16 * grp], 1,
                                     __ATOMIC_RELAXED, __HIP_MEMORY_SCOPE_AGENT);
    if (((old + 1) & (GMEM - 1)) == 0) {                 // group closer
      int oldG = __hip_atomic_fetch_add(&bar[0], 1,
                                        __ATOMIC_RELAXED, __HIP_MEMORY_SCOPE_AGENT);
      if (((oldG + 1) & (NG - 1)) == 0) {                // global closer
        #pragma unroll
        for (int q = 0; q < NG; ++q)
          __hip_atomic_store(&bar[160 + 16 * q], ep,
                             __ATOMIC_RELAXED, __HIP_MEMORY_SCOPE_AGENT);
      }
    }
    int guard = 0;
    while (__hip_atomic_load(&bar[160 + 16 * grp],
                             __ATOMIC_RELAXED, __HIP_MEMORY_SCOPE_AGENT) < ep) {
      __builtin_amdgcn_s_sleep(2);
      if (++guard > (1 << 20)) break;   // fail-visible, never hangs
    }
    __builtin_amdgcn_fence(__ATOMIC_ACQUIRE, "agent");   // inv once
  }
  __syncthreads();
}

__global__ __launch_bounds__(TPB, 2) void k_main(
    const float* __restrict__ x,  const float* __restrict__ wa,
    const float* __restrict__ ba, const float* __restrict__ lat,
    const float* __restrict__ tau,const float* __restrict__ we,
    const float* __restrict__ be, float* __restrict__ ws,
    float* __restrict__ out) {
  const int blk = blockIdx.x, tid = threadIdx.x;
  const int w = tid >> 6, lane = tid & 63;
  const int p = blk >> 6, g = blk & 63, grp = blk & 7;
  float* buf = ws;
  int* idxA = (int*)ws + OFF_IDX;
  int* bar  = (int*)ws + OFF_BAR;

  __shared__ float s_tc[8 * 128];    // pre-clipped tau slice (ho=w row)
  __shared__ float s_lat[8 * 128];
  __shared__ float s_wa[128 * 64];   // wa rows [p*128, p*128+128)
  __shared__ float s_h[8 * 128];     // h[b][il] slice for scat
  __shared__ float s_hdl[512];       // leader: full h_del of its sample
  __shared__ float s_red[256];       // leader: y partials
  __shared__ int   s_ptr[8], s_cidx[8], s_done8[8];

  // ---------------- init ----------------
  for (size_t i = (size_t)(blk * TPB + tid); i < SZ_BUF; i += (size_t)NBLK * TPB)
    buf[i] = 0.0f;
  for (int q = tid; q < 128 * 64; q += TPB)
    s_wa[q] = wa[(size_t)(p * 128 + (q >> 6)) * V + (q & 63)];
  for (int q = tid; q < 8 * 128; q += TPB) {
    int ww = q >> 7, il = q & 127;
    int ho = g * 8 + ww, i = p * 128 + il;
    float tv = tau[(size_t)ho * H + i];
    s_tc[q]  = fminf(fmaxf(tv, 1.0f), 48.0f);
    s_lat[q] = lat[(size_t)ho * H + i];
  }
  if (tid < 8) { s_ptr[tid] = 0; s_cidx[tid] = 0; s_done8[tid] = 0; }
  uint32_t ka = 0u, kb = (uint32_t)blk;
  if (blk < B) tf2x32(0u, 42u, ka, kb);     // leader sample key

  gbar(bar, grp, 1);

  // ---------------- 102 sequential steps ----------------
  for (int t = 0; t < NSTEP; ++t) {
    const bool thinkM = (t >= T && t < T + 9);
    const bool decM   = (t >= T + 9);

    // state update (replicated per block; thread b handles sample b)
    if (tid < 8 && t >= 1) {
      const int b = tid;
      const bool prevThink = (t - 1 >= T) && (t - 1 < T + 9);
      const bool aP = prevThink ? (s_done8[b] == 0) : true;
      if (t - 1 >= T) {
        int ix = idxA[(t - 1) * 8 + b];
        if (aP) s_cidx[b] = ix;
        if (prevThink && (ix == 63 || (t - 1 - T) == 8)) s_done8[b] = 1;
      }
      if (aP) { int pv = s_ptr[b]; s_ptr[b] = (pv + 1 == D1) ? 0 : pv + 1; }
    }
    __syncthreads();

    int actM = 0;
    #pragma unroll
    for (int b = 0; b < B; ++b)
      actM |= ((thinkM ? (s_done8[b] ^ 1) : 1) & 1) << b;

    // control: h-slice for this block's input chunk (+ leader full h_del)
    #pragma unroll
    for (int it2 = 0; it2 < 2; ++it2) {
      int q = tid + it2 * TPB;
      int b = q >> 7, il = q & 127;
      int j = p * 128 + il;
      size_t base = (size_t)(j >> 3) * 3136 + (size_t)s_ptr[b] * 64 + b * 8 + (j & 7);
      float h0 = buf[base];
      float h1 = buf[base + P2STRIDE];
      float h2 = buf[base + 2 * P2STRIDE];
      float h3 = buf[base + 3 * P2STRIDE];
      float hd = ((h0 + h1) + h2) + h3;
      float acc;
      if (t <= T) {      // encoder rows, and first think step uses x[:,T-1,:]
        const float* xr = x + ((size_t)b * T + (t < T ? t : T - 1)) * V;
        acc = ba[j] + hd;
        const float* war = &s_wa[il * 64];
        #pragma unroll
        for (int v = 0; v < V; v += 4) {
          float4 w4 = *(const float4*)(war + v);
          float4 x4 = *(const float4*)(xr + v);
          acc = fmaf(w4.x, x4.x, acc); acc = fmaf(w4.y, x4.y, acc);
          acc = fmaf(w4.z, x4.z, acc); acc = fmaf(w4.w, x4.w, acc);
        }
      } else {           // cur is exactly one-hot -> single add (bit-equal)
        acc = (ba[j] + hd) + s_wa[il * 64 + s_cidx[b]];
      }
      s_h[b * 128 + il] = tanhf(acc);
    }
    if (blk < B && t >= T) {   // leader: full h_del of own sample
      int j = tid;
      size_t base = (size_t)(j >> 3) * 3136 + (size_t)s_ptr[blk] * 64 + blk * 8 + (j & 7);
      float h0 = buf[base];
      float h1 = buf[base + P2STRIDE];
      float h2 = buf[base + 2 * P2STRIDE];
      float h3 = buf[base + 3 * P2STRIDE];
      s_hdl[j] = ((h0 + h1) + h2) + h3;
    }
    __syncthreads();

    // leader: y, out, gumbel argmax, idx store
    if (blk < B && t >= T) {
      if (tid < 256) {
        int o = tid >> 2, q2 = tid & 3;
        const float* wer = we + (size_t)o * H + q2 * 128;
        const float* hp  = &s_hdl[q2 * 128];
        float a2 = 0.0f;
        for (int i2 = 0; i2 < 128; i2 += 4) {
          float4 w4 = *(const float4*)(wer + i2);
          a2 = fmaf(w4.x, hp[i2],     a2); a2 = fmaf(w4.y, hp[i2 + 1], a2);
          a2 = fmaf(w4.z, hp[i2 + 2], a2); a2 = fmaf(w4.w, hp[i2 + 3], a2);
        }
        s_red[tid] = a2;
      }
      __syncthreads();
      if (tid < V) {
        const int o = tid, it = t - T;
        float y = ((s_red[o*4] + s_red[o*4+1]) + (s_red[o*4+2] + s_red[o*4+3])) + be[o];
        if (decM && o < V - 1)
          out[((size_t)blk * NDEC + (t - T - 9)) * (V - 1) + o] = y;
        uint32_t data = (it < 9) ? (uint32_t)it : (uint32_t)(10000 + (it - 9));
        uint32_t e = 0u, f = data; tf2x32(ka, kb, e, f);
        uint32_t r0 = 0u, r1 = (uint32_t)o; tf2x32(e, f, r0, r1);
        float bv = y + gumbel_from_bits(r0 ^ r1);
        int bi = o;
        #pragma unroll
        for (int m = 32; m >= 1; m >>= 1) {
          float ov = __shfl_xor(bv, m, 64);
          int   oi = __shfl_xor(bi, m, 64);
          if (ov > bv || (ov == bv && oi < bi)) { bv = ov; bi = oi; }
        }
        if (o == 0) idxA[t * 8 + blk] = bi;
      }
    }

    // scat: wave w owns output row ho=g*8+w, lane = delay d
    {
      const float dd = (float)lane;
      const float inv = 1.0f / 24.0f, inv2 = inv * inv;
      float acc[B];
      #pragma unroll
      for (int b = 0; b < B; ++b) acc[b] = 0.0f;
      const float* tcr = &s_tc[w * 128];
      const float* ltr = &s_lat[w * 128];
      for (int ii = 0; ii < 128; ii += 4) {
        float4 t4 = *(const float4*)(tcr + ii);
        float4 l4 = *(const float4*)(ltr + ii);
        float4 h4[B];
        #pragma unroll
        for (int b = 0; b < B; ++b) h4[b] = *(const float4*)(&s_h[b * 128 + ii]);
        const float* tp = (const float*)&t4;
        const float* lp = (const float*)&l4;
        #pragma unroll
        for (int k = 0; k < 4; ++k) {
          float tc = tp[k];
          float cr = fmaxf(0.0f, inv - fabsf((dd - tc) * inv2));
          float q2 = cr * lp[k];
          #pragma unroll
          for (int b = 0; b < B; ++b)
            acc[b] = fmaf(q2, ((const float*)&h4[b])[k], acc[b]);
        }
      }
      if (lane >= 1 && lane <= 48) {
        const size_t cbase = (size_t)(p * 64 + g) * 3136 + w;
        #pragma unroll
        for (int b = 0; b < B; ++b) {
          if ((actM >> b) & 1) {
            int slot = s_ptr[b] + lane; if (slot >= D1) slot -= D1;
            size_t a = cbase + (size_t)slot * 64 + b * 8;
            // d=48 is the FIRST contribution to a freshly-consumed slot:
            // overwrite implements the reference's slot-clear (deferred).
            float old = (lane == 48) ? 0.0f : buf[a];
            buf[a] = old + acc[b];
          }
        }
      }
    }

    gbar(bar, grp, t + 2);
  }
}

} // anonymous namespace

extern "C" void kernel_launch(void* const* d_in, const int* in_sizes, int n_in,
                              void* d_out, int out_size, void* d_ws, size_t ws_size,
                              hipStream_t stream) {
  (void)in_sizes; (void)n_in; (void)out_size; (void)ws_size;
  const float* x   = (const float*)d_in[0];
  const float* wa  = (const float*)d_in[1];
  const float* ba  = (const float*)d_in[2];
  const float* lat = (const float*)d_in[3];
  const float* tau = (const float*)d_in[4];
  const float* we  = (const float*)d_in[5];
  const float* be  = (const float*)d_in[6];
  float* out = (float*)d_out;
  float* ws  = (float*)d_ws;

  k_zero<<<dim3(1), dim3(512), 0, stream>>>(ws);
  k_main<<<dim3(NBLK), dim3(TPB), 0, stream>>>(x, wa, ba, lat, tau, we, be, ws, out);
}